// Round 10
// baseline (102.174 us; speedup 1.0000x reference)
//
#include <hip/hip_runtime.h>

typedef __bf16 bf16x8 __attribute__((ext_vector_type(8)));
typedef float f32x4 __attribute__((ext_vector_type(4)));

#define BN_EPS 1e-5f

__device__ __forceinline__ unsigned short f2bf(float f) {
    union { float f; unsigned u; } x; x.f = f;
    unsigned r = x.u + 0x7fffu + ((x.u >> 16) & 1u);
    return (unsigned short)(r >> 16);
}

__device__ __forceinline__ unsigned pk_bf16(float lo, float hi) {
    unsigned r;
    asm("v_cvt_pk_bf16_f32 %0, %1, %2" : "=v"(r) : "v"(lo), "v"(hi));
    return r;
}

__device__ __forceinline__ float fcomp(float4 v, int j) {
    return (j == 0) ? v.x : (j == 1) ? v.y : (j == 2) ? v.z : v.w;
}

// ---------------- prepass: fold BN scale into weights, FRAGMENT-CONTIGUOUS layout ----
// wfF[e]: frag for koct q=k/8, outch o at ((q*256 + o)*8 + (k&7)).
__global__ void prep_kernel(const float* __restrict__ pw0, const float* __restrict__ pw1,
                            const float* __restrict__ w2,
                            const float* __restrict__ s0, const float* __restrict__ b0,
                            const float* __restrict__ m0, const float* __restrict__ v0,
                            const float* __restrict__ s1, const float* __restrict__ b1,
                            const float* __restrict__ m1, const float* __restrict__ v1,
                            const float* __restrict__ s2, const float* __restrict__ b2,
                            const float* __restrict__ m2, const float* __restrict__ v2,
                            unsigned short* __restrict__ wfF0, unsigned short* __restrict__ wfF1,
                            unsigned short* __restrict__ wfF2, float* __restrict__ beta) {
    int o = blockIdx.x;     // 0..255 outch
    int t = threadIdx.x;    // 0..255 k
    float inv0 = s0[o] * rsqrtf(v0[o] + BN_EPS);
    float inv1 = s1[o] * rsqrtf(v1[o] + BN_EPS);
    float inv2 = s2[o] * rsqrtf(v2[o] + BN_EPS);
    if (t == 0) {
        beta[0 * 256 + o] = b0[o] - m0[o] * inv0;
        beta[1 * 256 + o] = b1[o] - m1[o] * inv1;
        beta[2 * 256 + o] = b2[o] - m2[o] * inv2;
    }
    if (t < 128) {
        wfF0[((t >> 3) * 256 + o) * 8 + (t & 7)] = f2bf(pw0[o * 128 + t] * inv0);
        wfF1[((t >> 3) * 256 + o) * 8 + (t & 7)] = f2bf(pw1[o * 128 + t] * inv1);
    }
    wfF2[((t >> 3) * 256 + o) * 8 + (t & 7)] = f2bf(w2[o * 256 + t] * inv2);
}

// ---------------- GEMM helpers ----------------
__device__ __forceinline__ void loadA0(const unsigned short* __restrict__ W,
                                       int wave, int l15, int l4, bf16x8 a[2]) {
    const int row0 = wave * 32 + l15;
    a[0] = *(const bf16x8*)(W + (l4 * 256 + row0) * 8);
    a[1] = *(const bf16x8*)(W + (l4 * 256 + row0 + 16) * 8);
}

// B-tile: [64 px][256 K] bf16, px-major 512 B/px, 16-B col c stored at c ^ ((px&15)<<4).
template<int NK>
__device__ __forceinline__ void gemm_expert(const char* lds, const unsigned short* __restrict__ W,
                                            int qb, int wave, int l15, int l4,
                                            const int* pxv, const int* swv,
                                            const bf16x8 aPre[2], f32x4 acc[2][4]) {
    const int row0 = wave * 32 + l15;
    bf16x8 aC[2], bC[4];
    aC[0] = aPre[0]; aC[1] = aPre[1];
#pragma unroll
    for (int tp = 0; tp < 4; ++tp)
        bC[tp] = *(const bf16x8*)(lds + pxv[tp] * 512 + ((qb + l4 * 16) ^ swv[tp]));

#pragma unroll
    for (int kk = 0; kk < NK; ++kk) {
        bf16x8 aN[2], bN[4];
        if (kk + 1 < NK) {
#pragma unroll
            for (int ot = 0; ot < 2; ++ot)
                aN[ot] = *(const bf16x8*)(W + (((kk + 1) * 4 + l4) * 256 + row0 + ot * 16) * 8);
#pragma unroll
            for (int tp = 0; tp < 4; ++tp)
                bN[tp] = *(const bf16x8*)(lds + pxv[tp] * 512 + ((qb + (kk + 1) * 64 + l4 * 16) ^ swv[tp]));
        }
#pragma unroll
        for (int ot = 0; ot < 2; ++ot)
#pragma unroll
            for (int tp = 0; tp < 4; ++tp)
                acc[ot][tp] = __builtin_amdgcn_mfma_f32_16x16x32_bf16(aC[ot], bC[tp], acc[ot][tp], 0, 0, 0);
        if (kk + 1 < NK) {
#pragma unroll
            for (int ot = 0; ot < 2; ++ot) aC[ot] = aN[ot];
#pragma unroll
            for (int tp = 0; tp < 4; ++tp) bC[tp] = bN[tp];
        }
    }
}

__device__ __forceinline__ void epilogue(const f32x4 acc[2][4], float ce, const float* __restrict__ bp,
                                         int wave, int l4, f32x4 res[2][4]) {
#pragma unroll
    for (int ot = 0; ot < 2; ++ot)
#pragma unroll
        for (int j = 0; j < 4; ++j) {
            const int o = wave * 32 + ot * 16 + l4 * 4 + j;
            const float bet = bp[o];
#pragma unroll
            for (int tp = 0; tp < 4; ++tp) {
                float v = acc[ot][tp][j] + bet;
                float sig = __builtin_amdgcn_rcpf(1.f + __expf(-v));
                res[ot][tp][j] += ce * (v * sig);
            }
        }
}

// ---------------- main fused kernel: 1 WG per (b,h) row, 8 waves ----------
// LDS: [0,32K) dw B-tile; [32K,64K) raw B-tile; [68K,80K) dw weights (48 B/ch);
// transpose epilogue reuses [0,68K).
__global__ __launch_bounds__(512, 4)
void fused_kernel(const float* __restrict__ x,
                  const float* __restrict__ wts, const int* __restrict__ idx,
                  const float* __restrict__ dw0, const float* __restrict__ dw1,
                  const unsigned short* __restrict__ wfF0,
                  const unsigned short* __restrict__ wfF1,
                  const unsigned short* __restrict__ wfF2,
                  const float* __restrict__ beta,
                  float* __restrict__ out) {
    __shared__ __align__(16) char lds[81920];

    const int tid  = threadIdx.x;
    const int wave = tid >> 6;
    const int lane = tid & 63;

    // XCD-aware swizzle (r8, proven: FETCH 52 vs 116 MB against balance-first)
    const int bid = blockIdx.x;
    const int nb  = ((bid & 7) << 8) | (bid >> 3);   // bijective on 2048
    const int b   = nb >> 6;
    const int h   = nb & 63;

    float c0 = 0.f, c1 = 0.f, c2 = 0.f;
#pragma unroll
    for (int t = 0; t < 2; ++t) {
        int e = idx[b * 2 + t];
        float w = wts[b * 2 + t];
        if (e == 0) c0 += w;
        else if (e == 1) c1 += w;
        else if (e == 2) c2 += w;
    }
    const bool do0 = (c0 != 0.f), do1 = (c1 != 0.f), do2 = (c2 != 0.f);

    const long rowBase = (long)b * 1048576L;

    const int g   = lane >> 2;                       // px-group 0..15
    const int kq  = lane & 3;
    const int px0 = g * 4;
    const int l15 = lane & 15;
    const int l4  = lane >> 4;
    const float* xb = x + rowBase + h * 64 + px0;
    const bool hm = (h > 0), hp = (h < 63);

    f32x4 res[2][4];
#pragma unroll
    for (int ot = 0; ot < 2; ++ot)
#pragma unroll
        for (int tp = 0; tp < 4; ++tp)
            res[ot][tp] = (f32x4){0.f, 0.f, 0.f, 0.f};

    int pxv[4], swv[4];
#pragma unroll
    for (int tp = 0; tp < 4; ++tp) {
        pxv[tp] = tp * 16 + l15;
        swv[tp] = (pxv[tp] & 15) << 4;
    }

    // ---- stage dw weights into LDS, padded 48 B per channel (aligned reads) ----
    float* ldw = (float*)(lds + 69632);
    if (do0 || do1) {
#pragma unroll
        for (int r = 0; r < 6; ++r) {
            const int t  = tid + r * 512;            // 0..3071
            const int ch = t / 12;
            const int c9 = t - ch * 12;
            float v = 0.f;
            if (c9 < 9) v = (ch < 128) ? dw0[ch * 9 + c9] : dw1[(ch - 128) * 9 + c9];
            ldw[t] = v;
        }
    }

    const bool dwact = (wave < 4) ? do0 : do1;
    const bool stg = dwact || do2;
    const float4 z4 = make_float4(0.f, 0.f, 0.f, 0.f);

    // 2-deep pipelined staging: pair p+1's loads in flight during pair p's compute
    float4 cm0, cc0, cp0, cm1, cc1, cp1;
    float4 nm0, nc0, np0, nm1, nc1, np1;
    if (stg) {
        const int k = wave * 32 + kq * 4;            // pair 0
        const float* x0 = xb + (long)k * 4096;
        const float* x1 = x0 + 4096;
        cc0 = *(const float4*)x0;
        cc1 = *(const float4*)x1;
        cm0 = (dwact && hm) ? *(const float4*)(x0 - 64) : z4;
        cp0 = (dwact && hp) ? *(const float4*)(x0 + 64) : z4;
        cm1 = (dwact && hm) ? *(const float4*)(x1 - 64) : z4;
        cp1 = (dwact && hp) ? *(const float4*)(x1 + 64) : z4;
    }
    __syncthreads();                                 // weight LDS ready; pair-0 loads in flight

    if (stg) {
#pragma unroll
        for (int p = 0; p < 4; ++p) {
            const int k = wave * 32 + ((p >> 1) << 4) + kq * 4 + ((p & 1) << 1);
            if (p < 3) {
                const int pn = p + 1;
                const int kn = wave * 32 + ((pn >> 1) << 4) + kq * 4 + ((pn & 1) << 1);
                const float* x0 = xb + (long)kn * 4096;
                const float* x1 = x0 + 4096;
                nc0 = *(const float4*)x0;
                nc1 = *(const float4*)x1;
                nm0 = (dwact && hm) ? *(const float4*)(x0 - 64) : z4;
                np0 = (dwact && hp) ? *(const float4*)(x0 + 64) : z4;
                nm1 = (dwact && hm) ? *(const float4*)(x1 - 64) : z4;
                np1 = (dwact && hp) ? *(const float4*)(x1 + 64) : z4;
            }
            const int colb = (k >> 3) * 16;
            const int sub  = (k & 7) * 2;
            if (dwact) {
                float y0[4], y1[4];
                {
                    const float* wp = ldw + k * 12;
                    const float w0 = wp[0], w1 = wp[1], w2 = wp[2];
                    const float w3 = wp[3], w4 = wp[4], w5 = wp[5];
                    const float w6 = wp[6], w7 = wp[7], w8 = wp[8];
                    float lm = __shfl_up(cm0.w, 4), lc = __shfl_up(cc0.w, 4), lp = __shfl_up(cp0.w, 4);
                    float Rm = __shfl_down(cm0.x, 4), Rc = __shfl_down(cc0.x, 4), Rp = __shfl_down(cp0.x, 4);
                    if (g == 0)  { lm = 0.f; lc = 0.f; lp = 0.f; }
                    if (g == 15) { Rm = 0.f; Rc = 0.f; Rp = 0.f; }
                    y0[0] = w0*lm    + w1*cm0.x + w2*cm0.y + w3*lc    + w4*cc0.x + w5*cc0.y + w6*lp    + w7*cp0.x + w8*cp0.y;
                    y0[1] = w0*cm0.x + w1*cm0.y + w2*cm0.z + w3*cc0.x + w4*cc0.y + w5*cc0.z + w6*cp0.x + w7*cp0.y + w8*cp0.z;
                    y0[2] = w0*cm0.y + w1*cm0.z + w2*cm0.w + w3*cc0.y + w4*cc0.z + w5*cc0.w + w6*cp0.y + w7*cp0.z + w8*cp0.w;
                    y0[3] = w0*cm0.z + w1*cm0.w + w2*Rm    + w3*cc0.z + w4*cc0.w + w5*Rc    + w6*cp0.z + w7*cp0.w + w8*Rp;
                }
                {
                    const float* wp = ldw + (k + 1) * 12;
                    const float w0 = wp[0], w1 = wp[1], w2 = wp[2];
                    const float w3 = wp[3], w4 = wp[4], w5 = wp[5];
                    const float w6 = wp[6], w7 = wp[7], w8 = wp[8];
                    float lm = __shfl_up(cm1.w, 4), lc = __shfl_up(cc1.w, 4), lp = __shfl_up(cp1.w, 4);
                    float Rm = __shfl_down(cm1.x, 4), Rc = __shfl_down(cc1.x, 4), Rp = __shfl_down(cp1.x, 4);
                    if (g == 0)  { lm = 0.f; lc = 0.f; lp = 0.f; }
                    if (g == 15) { Rm = 0.f; Rc = 0.f; Rp = 0.f; }
                    y1[0] = w0*lm    + w1*cm1.x + w2*cm1.y + w3*lc    + w4*cc1.x + w5*cc1.y + w6*lp    + w7*cp1.x + w8*cp1.y;
                    y1[1] = w0*cm1.x + w1*cm1.y + w2*cm1.z + w3*cc1.x + w4*cc1.y + w5*cc1.z + w6*cp1.x + w7*cp1.y + w8*cp1.z;
                    y1[2] = w0*cm1.y + w1*cm1.z + w2*cm1.w + w3*cc1.y + w4*cc1.z + w5*cc1.w + w6*cp1.y + w7*cp1.z + w8*cp1.w;
                    y1[3] = w0*cm1.z + w1*cm1.w + w2*Rm    + w3*cc1.z + w4*cc1.w + w5*Rc    + w6*cp1.z + w7*cp1.w + w8*Rp;
                }
#pragma unroll
                for (int j = 0; j < 4; ++j) {
                    const int px = px0 + j;
                    *(unsigned*)(lds + px * 512 + ((colb ^ ((px & 15) << 4))) + sub) =
                        pk_bf16(y0[j], y1[j]);
                }
            }
            if (do2) {
#pragma unroll
                for (int j = 0; j < 4; ++j) {
                    const int px = px0 + j;
                    *(unsigned*)(lds + 32768 + px * 512 + ((colb ^ ((px & 15) << 4))) + sub) =
                        pk_bf16(fcomp(cc0, j), fcomp(cc1, j));
                }
            }
            if (p < 3) {
                cm0 = nm0; cc0 = nc0; cp0 = np0;
                cm1 = nm1; cc1 = nc1; cp1 = np1;
            }
        }
    }

    // first A-frags for e0 hide under the barrier drain
    bf16x8 a0[2];
    loadA0(wfF0, wave, l15, l4, a0);

    __syncthreads();

    // ============ GEMM phases with next-expert A prefetch under epilogue ============
    f32x4 acc[2][4];
    if (do0) {
#pragma unroll
        for (int ot = 0; ot < 2; ++ot)
#pragma unroll
            for (int tp = 0; tp < 4; ++tp) acc[ot][tp] = (f32x4){0.f, 0.f, 0.f, 0.f};
        gemm_expert<4>(lds, wfF0, 0, wave, l15, l4, pxv, swv, a0, acc);
    }
    bf16x8 a1[2];
    loadA0(wfF1, wave, l15, l4, a1);
    if (do0) epilogue(acc, c0, beta, wave, l4, res);

    if (do1) {
#pragma unroll
        for (int ot = 0; ot < 2; ++ot)
#pragma unroll
            for (int tp = 0; tp < 4; ++tp) acc[ot][tp] = (f32x4){0.f, 0.f, 0.f, 0.f};
        gemm_expert<4>(lds, wfF1, 256, wave, l15, l4, pxv, swv, a1, acc);
    }
    bf16x8 a2[2];
    loadA0(wfF2, wave, l15, l4, a2);
    if (do1) epilogue(acc, c1, beta + 256, wave, l4, res);

    if (do2) {
#pragma unroll
        for (int ot = 0; ot < 2; ++ot)
#pragma unroll
            for (int tp = 0; tp < 4; ++tp) acc[ot][tp] = (f32x4){0.f, 0.f, 0.f, 0.f};
        gemm_expert<8>(lds + 32768, wfF2, 0, wave, l15, l4, pxv, swv, a2, acc);
        epilogue(acc, c2, beta + 512, wave, l4, res);
    }

    // ============ store: both outch halves in one transpose round ============
    float* lf = (float*)lds;
    const long outB = rowBase + h * 64;
    __syncthreads();
    {
        const int reg   = wave >> 2;                 // 0 or 1
        const int rbase = reg * 8704;
#pragma unroll
        for (int ot = 0; ot < 2; ++ot)
#pragma unroll
            for (int j = 0; j < 4; ++j) {
                const int row = (wave & 3) * 32 + ot * 16 + l4 * 4 + j;  // 0..127
#pragma unroll
                for (int tp = 0; tp < 4; ++tp)
                    lf[rbase + row * 68 + tp * 16 + l15] = res[ot][tp][j];
            }
    }
    __syncthreads();
    {
        const int rowq = tid >> 3;                   // 0..63
        const int col  = (tid & 7) * 8;              // float index
#pragma unroll
        for (int rr = 0; rr < 4; ++rr) {
            const int lr = rowq + rr * 64;           // 0..255
            const int ad = (lr >> 7) * 8704 + (lr & 127) * 68 + col;
            float4 v0 = *(float4*)&lf[ad];
            float4 v1 = *(float4*)&lf[ad + 4];
            float* op = out + outB + (long)lr * 4096 + col;
            *(float4*)op = v0;
            *(float4*)(op + 4) = v1;
        }
    }
}

extern "C" void kernel_launch(void* const* d_in, const int* in_sizes, int n_in,
                              void* d_out, int out_size, void* d_ws, size_t ws_size,
                              hipStream_t stream) {
    const float* x    = (const float*)d_in[0];
    const float* wts  = (const float*)d_in[1];
    const int*   idx  = (const int*)d_in[2];
    const float* dw0  = (const float*)d_in[3];
    const float* pw0  = (const float*)d_in[4];
    const float* s0   = (const float*)d_in[5];
    const float* b0   = (const float*)d_in[6];
    const float* m0   = (const float*)d_in[7];
    const float* v0   = (const float*)d_in[8];
    const float* dw1  = (const float*)d_in[9];
    const float* pw1  = (const float*)d_in[10];
    const float* s1   = (const float*)d_in[11];
    const float* b1   = (const float*)d_in[12];
    const float* m1   = (const float*)d_in[13];
    const float* v1   = (const float*)d_in[14];
    const float* w2   = (const float*)d_in[15];
    const float* s2   = (const float*)d_in[16];
    const float* b2   = (const float*)d_in[17];
    const float* m2   = (const float*)d_in[18];
    const float* v2   = (const float*)d_in[19];

    char* ws = (char*)d_ws;
    unsigned short* wfF0 = (unsigned short*)ws;                 // 64 KB
    unsigned short* wfF1 = (unsigned short*)(ws + 65536);       // 64 KB
    unsigned short* wfF2 = (unsigned short*)(ws + 131072);      // 128 KB
    float*          beta = (float*)(ws + 262144);               // 3 KB

    prep_kernel<<<256, 256, 0, stream>>>(pw0, pw1, w2,
                                         s0, b0, m0, v0,
                                         s1, b1, m1, v1,
                                         s2, b2, m2, v2,
                                         wfF0, wfF1, wfF2, beta);

    fused_kernel<<<2048, 512, 0, stream>>>(x, wts, idx, dw0, dw1,
                                           wfF0, wfF1, wfF2, beta, (float*)d_out);
}